// Round 1
// baseline (753.551 us; speedup 1.0000x reference)
//
#include <hip/hip_runtime.h>
#include <stdint.h>
#include <stddef.h>

typedef _Float16 half_t;
typedef _Float16 half2_t __attribute__((ext_vector_type(2)));
typedef _Float16 half8_t __attribute__((ext_vector_type(8)));
typedef float    floatx4 __attribute__((ext_vector_type(4)));
typedef uint32_t u32x4   __attribute__((ext_vector_type(4)));
typedef int      intx4   __attribute__((ext_vector_type(4)));

#define SEQ_L 512
#define NBATCH 64
#define DIM 256
#define NTOT (NBATCH * SEQ_L)   // 32768 rows

// ---------- helpers ----------
__device__ __forceinline__ int dot4i8(uint32_t a, uint32_t b, int c) {
#if defined(__has_builtin)
#if __has_builtin(__builtin_amdgcn_sdot4)
  return __builtin_amdgcn_sdot4((int)a, (int)b, c, false);
#else
  int s = c;
  s += (int)(int8_t)(a)       * (int)(int8_t)(b);
  s += (int)(int8_t)(a >> 8)  * (int)(int8_t)(b >> 8);
  s += (int)(int8_t)(a >> 16) * (int)(int8_t)(b >> 16);
  s += (int)(int8_t)(a >> 24) * (int)(int8_t)(b >> 24);
  return s;
#endif
#else
  int s = c;
  s += (int)(int8_t)(a)       * (int)(int8_t)(b);
  s += (int)(int8_t)(a >> 8)  * (int)(int8_t)(b >> 8);
  s += (int)(int8_t)(a >> 16) * (int)(int8_t)(b >> 16);
  s += (int)(int8_t)(a >> 24) * (int)(int8_t)(b >> 24);
  return s;
#endif
}

__device__ __forceinline__ float sigmoidf_fast(float x) {
  return 1.0f / (1.0f + __expf(-x));
}
__device__ __forceinline__ float tanhf_fast(float x) {
  float e = __expf(2.0f * x);
  return 1.0f - 2.0f / (e + 1.0f);
}

// ---------- kernel 1: W -> f16, transposed to [768 n][256 k] ----------
__global__ void conv_w_kernel(const float* __restrict__ Wr,
                              const float* __restrict__ Wz,
                              const float* __restrict__ Wh,
                              half_t* __restrict__ Wt) {
  int n = blockIdx.x;          // 0..767
  int k = threadIdx.x;         // 0..255
  const float* W = (n < 256) ? Wr : ((n < 512) ? Wz : Wh);
  int j = n & 255;
  Wt[(size_t)n * DIM + k] = (half_t)W[(size_t)k * DIM + j];
}

// ---------- kernel 2: a = sigmoid(x@k1 - x@k2) per row ----------
__global__ __launch_bounds__(256) void attn_a_kernel(const float* __restrict__ inp,
                                                     const float* __restrict__ k1,
                                                     const float* __restrict__ k2,
                                                     float* __restrict__ a_arr) {
  int row  = blockIdx.x * 4 + (threadIdx.x >> 6);
  int lane = threadIdx.x & 63;
  const float4* x4 = (const float4*)(inp + (size_t)row * DIM);
  float4 xv  = x4[lane];
  float4 k1v = ((const float4*)k1)[lane];
  float4 k2v = ((const float4*)k2)[lane];
  float e1 = xv.x * k1v.x + xv.y * k1v.y + xv.z * k1v.z + xv.w * k1v.w;
  float e2 = xv.x * k2v.x + xv.y * k2v.y + xv.z * k2v.z + xv.w * k2v.w;
#pragma unroll
  for (int off = 32; off >= 1; off >>= 1) {
    e1 += __shfl_xor(e1, off);
    e2 += __shfl_xor(e2, off);
  }
  if (lane == 0) a_arr[row] = 1.0f / (1.0f + __expf(e2 - e1));
}

// ---------- kernel 2b: per-(gate,col) |U| max -> scale = max/127 ----------
__global__ __launch_bounds__(256) void uscale_kernel(const float* __restrict__ Ur,
                                                     const float* __restrict__ Uz,
                                                     const float* __restrict__ Uh,
                                                     float* __restrict__ su) {
  const int g = blockIdx.x;    // 0..2
  const int j = threadIdx.x;   // 0..255
  const float* U = (g == 0) ? Ur : ((g == 1) ? Uz : Uh);
  float m = 0.0f;
  for (int k = 0; k < DIM; ++k) m = fmaxf(m, fabsf(U[(size_t)k * DIM + j]));
  su[g * DIM + j] = fmaxf(m, 1e-30f) * (1.0f / 127.0f);
}

// ---------- kernel 2c: pack U -> i8 quads, layout Ui8[g][quad=k/4][j] ----------
__global__ __launch_bounds__(256) void upack_kernel(const float* __restrict__ Ur,
                                                    const float* __restrict__ Uz,
                                                    const float* __restrict__ Uh,
                                                    const float* __restrict__ su,
                                                    uint32_t* __restrict__ Ui8) {
  const int g = blockIdx.x;    // 0..2
  const int j = threadIdx.x;   // 0..255
  const float* U = (g == 0) ? Ur : ((g == 1) ? Uz : Uh);
  const float r = 1.0f / su[g * DIM + j];   // = 127/max
  for (int q = 0; q < 64; ++q) {
    uint32_t w = 0;
#pragma unroll
    for (int t = 0; t < 4; ++t) {
      float v = U[(size_t)(q * 4 + t) * DIM + j] * r;
      int mi = __float2int_rn(v);
      mi = mi < -127 ? -127 : (mi > 127 ? 127 : mi);
      w |= ((uint32_t)(mi & 0xFF)) << (8 * t);
    }
    Ui8[((size_t)g * 64 + q) * DIM + j] = w;
  }
}

// ---------- kernel 3: P = X @ [Wr|Wz|Wh]  (MFMA f16, f32 acc, store f16) ----------
__global__ __launch_bounds__(256) void gemm_p_kernel(const float* __restrict__ X,
                                                     const half_t* __restrict__ Wt,
                                                     half_t* __restrict__ P) {
  __shared__ __align__(16) half_t As[128][32];
  __shared__ __align__(16) half_t Bs[128][32];
  const int tid  = threadIdx.x;
  const int bm   = blockIdx.x * 128;
  const int bn   = blockIdx.y * 128;
  const int lane = tid & 63;
  const int wave = tid >> 6;
  const int wm   = (wave >> 1) * 64;
  const int wn   = (wave & 1) * 64;
  const int quad = lane >> 4;
  const int l15  = lane & 15;
  const int r0   = tid >> 2;
  const int kc   = (tid & 3) * 8;

  floatx4 acc[4][4] = {};

  for (int k0 = 0; k0 < DIM; k0 += 32) {
#pragma unroll
    for (int hh = 0; hh < 2; ++hh) {
      int r = r0 + hh * 64;
      const float* asrc = X + (size_t)(bm + r) * DIM + k0 + kc;
      float4 f0 = *(const float4*)(asrc);
      float4 f1 = *(const float4*)(asrc + 4);
      half8_t av;
      av[0] = (half_t)f0.x; av[1] = (half_t)f0.y; av[2] = (half_t)f0.z; av[3] = (half_t)f0.w;
      av[4] = (half_t)f1.x; av[5] = (half_t)f1.y; av[6] = (half_t)f1.z; av[7] = (half_t)f1.w;
      *(half8_t*)(&As[r][kc]) = av;
      *(half8_t*)(&Bs[r][kc]) = *(const half8_t*)(Wt + (size_t)(bn + r) * DIM + k0 + kc);
    }
    __syncthreads();
    half8_t af[4], bf[4];
#pragma unroll
    for (int mi = 0; mi < 4; ++mi)
      af[mi] = *(const half8_t*)(&As[wm + mi * 16 + l15][quad * 8]);
#pragma unroll
    for (int ni = 0; ni < 4; ++ni)
      bf[ni] = *(const half8_t*)(&Bs[wn + ni * 16 + l15][quad * 8]);
#pragma unroll
    for (int mi = 0; mi < 4; ++mi)
#pragma unroll
      for (int ni = 0; ni < 4; ++ni)
        acc[mi][ni] = __builtin_amdgcn_mfma_f32_16x16x32_f16(af[mi], bf[ni], acc[mi][ni], 0, 0, 0);
    __syncthreads();
  }
#pragma unroll
  for (int mi = 0; mi < 4; ++mi)
#pragma unroll
    for (int ni = 0; ni < 4; ++ni) {
      int col = bn + wn + ni * 16 + l15;
#pragma unroll
      for (int rr = 0; rr < 4; ++rr) {
        int row = bm + wm + mi * 16 + quad * 4 + rr;
        P[(size_t)row * 768 + col] = (half_t)acc[mi][ni][rr];
      }
    }
}

// ---------- kernel 4: recurrence ----------
// Restructured this round:
//  * Pair-lane K-split: thread pair (2j, 2j+1) owns column j, K-halves 0/1.
//    Partial combine = 3x __shfl_xor(..,1) (DPP, register-only). The old
//    part[] LDS round-trip and barrier B1 are gone -> ONE barrier per step
//    with a double-buffered 2x64-u32 mt buffer.
//  * U window (96 u32 of packed i8 per thread) PINNED into arch VGPRs via
//    empty asm. Previous build reported VGPR_Count=88 < 96 -> U was being
//    re-fetched (or AGPR-shuttled) every step; that was the hidden per-step
//    cost (2625 cyc/step measured vs ~900 modeled).
//  * coref hist read hoisted above the dot phase (only depends on steps < i;
//    the c-1==i case selects this step's h in registers).
//  * h stored straight to global from odd lanes (fire-and-forget); ring
//    buffer, flush loop and tail removed.
__global__ __launch_bounds__(512, 2) void recur_kernel(
    const half_t* __restrict__ P,     // [32768, 768] f16 (xWr | xWz | xWh)
    const float* __restrict__ a_arr,  // [32768]
    const int* __restrict__ cidx,     // [32768]
    const uint32_t* __restrict__ Ui8, // [3][64][256] packed i8 quads
    const float* __restrict__ su,     // [3][256] scales (max/127)
    const float* __restrict__ br, const float* __restrict__ bz, const float* __restrict__ bh,
    float* __restrict__ out) {        // [32768, 256] f32
  const int tid  = threadIdx.x;
  const int j    = tid >> 1;          // 0..255 (column)
  const int half = tid & 1;           // K-half: quads [half*32, half*32+32)

  __shared__ __align__(16) half_t   hist[SEQ_L][128];  // 128 KB
  __shared__ __align__(16) uint32_t mtb[2][64];        // 512 B, double-buffered mt (i8)

  // ---- register-resident U window: 24 u32x4 = 96 u32 of i8 quads ----
  u32x4 ur8[8], uz8[8], uh8[8];
#pragma unroll
  for (int c8 = 0; c8 < 8; ++c8) {
#pragma unroll
    for (int t = 0; t < 4; ++t) {
      const int quad = half * 32 + c8 * 4 + t;
      ur8[c8][t] = Ui8[((size_t)0 * 64 + quad) * DIM + j];
      uz8[c8][t] = Ui8[((size_t)1 * 64 + quad) * DIM + j];
      uh8[c8][t] = Ui8[((size_t)2 * 64 + quad) * DIM + j];
    }
  }
  // Pin the window into arch VGPRs: the compiler may no longer sink/remat
  // these loads into the step loop (that re-fetch was the round-0 bottleneck).
#pragma unroll
  for (int c8 = 0; c8 < 8; ++c8) {
    asm volatile("" : "+v"(ur8[c8]), "+v"(uz8[c8]), "+v"(uh8[c8]));
  }

  const float scr = su[0 * DIM + j] * (1.0f / 127.0f);
  const float scz = su[1 * DIM + j] * (1.0f / 127.0f);
  const float sch = su[2 * DIM + j] * (1.0f / 127.0f);
  const float brj = br[j], bzj = bz[j], bhj = bh[j];

  // step 0 has mt == 0 (h0 = 0, c0 = 0)
  if (tid < 64) mtb[0][tid] = 0u;

  float mtj = 0.0f;                   // this thread's current-step mt[j] (f32 exact)
  const int base = blockIdx.x * SEQ_L;

  // ---- prefetch state for step 0 (all threads: both pair lanes compute) ----
  const half_t* prow0 = P + (size_t)base * 768;
  float pr_c = (float)prow0[j];
  float pz_c = (float)prow0[DIM + j];
  float ph_c = (float)prow0[2 * DIM + j];
  float a_n = a_arr[base + 1];
  int   c_n = cidx[base + 1];

  __syncthreads();

  for (int i = 0; i < SEQ_L; ++i) {
    // ---- next-step global prefetch; consumed a full step later ----
    const int ip1 = (i + 1 < SEQ_L) ? (i + 1) : i;
    const half_t* prow = P + (size_t)(base + ip1) * 768;
    float pr_x = (float)prow[j];
    float pz_x = (float)prow[DIM + j];
    float ph_x = (float)prow[2 * DIM + j];
    const int ip2 = (i + 2 < SEQ_L) ? (i + 2) : (SEQ_L - 1);
    const float a_x = a_arr[base + ip2];
    const int   c_x = cidx[base + ip2];

    // ---- coref prefetch for next step's mt: overlaps the dot phase ----
    const int  cp    = c_n - 1;          // <= i (valid coref constraint)
    const bool use_h = (cp == i);        // wave-uniform
    float corefv = 0.0f;
    if (j >= 128) {                      // waves 4..7, wave-uniform
      if (c_n > 0 && !use_h) corefv = (float)hist[cp][j - 128];
    }

    // ---- i8 dots over this thread's 128-element K-half ----
    int ar = 0, az = 0, ah = 0;
    const u32x4* mq = (const u32x4*)(&mtb[i & 1][half * 32]);
#pragma unroll
    for (int c8 = 0; c8 < 8; ++c8) {
      u32x4 m4 = mq[c8];                 // ds_read_b128, same-addr broadcast
      ar = dot4i8(m4.x, ur8[c8][0], ar);
      az = dot4i8(m4.x, uz8[c8][0], az);
      ah = dot4i8(m4.x, uh8[c8][0], ah);
      ar = dot4i8(m4.y, ur8[c8][1], ar);
      az = dot4i8(m4.y, uz8[c8][1], az);
      ah = dot4i8(m4.y, uh8[c8][1], ah);
      ar = dot4i8(m4.z, ur8[c8][2], ar);
      az = dot4i8(m4.z, uz8[c8][2], az);
      ah = dot4i8(m4.z, uh8[c8][2], ah);
      ar = dot4i8(m4.w, ur8[c8][3], ar);
      az = dot4i8(m4.w, uz8[c8][3], az);
      ah = dot4i8(m4.w, uh8[c8][3], ah);
    }
    // pair combine: lanes 2j / 2j+1 hold K-half partials -> DPP xor-1 add
    ar += __shfl_xor(ar, 1);
    az += __shfl_xor(az, 1);
    ah += __shfl_xor(ah, 1);

    const float fr = (float)ar * scr;
    const float fz = (float)az * scz;
    const float fh = (float)ah * sch;
    const float rg = sigmoidf_fast(pr_c + brj + fr);
    const float zg = sigmoidf_fast(pz_c + bzj + fz);
    const float hb = tanhf_fast(ph_c + bhj + rg * fh);
    const float h  = (1.0f - zg) * mtj + zg * hb;

    // ---- writes: odd lane stores h (global, fire-and-forget) + hist ----
    if (tid & 1) {
      out[(size_t)(base + i) * DIM + j] = h;
      if (j >= 128) hist[i][j - 128] = (half_t)h;
    }

    // ---- next step's mt (f32 exact for the recurrent path) ----
    float mtn;
    if (j < 128) {
      mtn = a_n * h;
    } else {
      const float coref = (c_n > 0) ? (use_h ? h : corefv) : 0.0f;
      mtn = (1.0f - a_n) * coref;
    }
    mtj = mtn;

    // ---- quantize + pack 4 columns' bytes -> one u32 (|mt| <= 1) ----
    // byte for column j lives (identically) in pair lanes 2j, 2j+1;
    // gather across lanes differing in bit1 (xor 2) then bit2 (xor 4).
    int mi = __float2int_rn(mtn * 127.0f);
    mi = mi < -127 ? -127 : (mi > 127 ? 127 : mi);
    unsigned v0 = (unsigned)mi & 0xFFu;
    unsigned o1 = (unsigned)__shfl_xor((int)v0, 2) & 0xFFu;   // byte of j^1
    unsigned pp = (j & 1) ? (o1 | (v0 << 8)) : (v0 | (o1 << 8));
    unsigned o2 = (unsigned)__shfl_xor((int)pp, 4);           // halfword of j^2 pair
    unsigned qd = (j & 2) ? ((o2 & 0xFFFFu) | (pp << 16))
                          : ((pp & 0xFFFFu) | (o2 << 16));
    if ((tid & 7) == 0) mtb[(i + 1) & 1][j >> 2] = qd;

    // rotate prefetch registers
    pr_c = pr_x; pz_c = pz_x; ph_c = ph_x;
    a_n = a_x;   c_n = c_x;

    // single barrier: publishes mtb[(i+1)&1] + hist[i]; separates step i
    // reads of mtb[i&1] from step i+1 writes into the same buffer.
    __syncthreads();
  }
}

// ---------- launcher ----------
extern "C" void kernel_launch(void* const* d_in, const int* in_sizes, int n_in,
                              void* d_out, int out_size, void* d_ws, size_t ws_size,
                              hipStream_t stream) {
  const float* inp = (const float*)d_in[0];
  const int*   ci  = (const int*)d_in[1];
  const float* Wr  = (const float*)d_in[2];
  const float* br  = (const float*)d_in[3];
  const float* Ur  = (const float*)d_in[4];
  const float* Wz  = (const float*)d_in[5];
  const float* bz  = (const float*)d_in[6];
  const float* Uz  = (const float*)d_in[7];
  const float* Wh  = (const float*)d_in[8];
  const float* bh  = (const float*)d_in[9];
  const float* Uh  = (const float*)d_in[10];
  const float* k1  = (const float*)d_in[11];
  const float* k2  = (const float*)d_in[12];
  float* out = (float*)d_out;

  char* ws = (char*)d_ws;
  // ws carve: Wt f16 [768*256] | P f16 [32768*768] | a f32 [32768]
  //           | su f32 [3*256] | Ui8 u32 [3*64*256]
  half_t*   Wt    = (half_t*)ws;                               // 393216 B
  half_t*   P     = (half_t*)(ws + 393216);                    // 50331648 B
  float*    a_arr = (float*)(ws + 393216 + 50331648);          // 131072 B
  float*    su    = (float*)(ws + 50855936);                   // 3072 B
  uint32_t* Ui8   = (uint32_t*)(ws + 50859008);                // 196608 B

  conv_w_kernel<<<dim3(768), dim3(256), 0, stream>>>(Wr, Wz, Wh, Wt);
  attn_a_kernel<<<dim3(NTOT / 4), dim3(256), 0, stream>>>(inp, k1, k2, a_arr);
  uscale_kernel<<<dim3(3), dim3(256), 0, stream>>>(Ur, Uz, Uh, su);
  upack_kernel<<<dim3(3), dim3(256), 0, stream>>>(Ur, Uz, Uh, su, Ui8);
  gemm_p_kernel<<<dim3(NTOT / 128, 6), dim3(256), 0, stream>>>(inp, Wt, P);
  recur_kernel<<<dim3(NBATCH), dim3(512), 0, stream>>>(P, a_arr, ci, Ui8, su,
                                                       br, bz, bh, out);
}

// Round 3
// 665.138 us; speedup vs baseline: 1.1329x; 1.1329x over previous
//
#include <hip/hip_runtime.h>
#include <stdint.h>
#include <stddef.h>

typedef _Float16 half_t;
typedef _Float16 half2_t __attribute__((ext_vector_type(2)));
typedef _Float16 half8_t __attribute__((ext_vector_type(8)));
typedef float    floatx4 __attribute__((ext_vector_type(4)));
typedef uint32_t u32x4   __attribute__((ext_vector_type(4)));
typedef int      intx4   __attribute__((ext_vector_type(4)));

#define SEQ_L 512
#define NBATCH 64
#define DIM 256
#define NTOT (NBATCH * SEQ_L)   // 32768 rows

// ---------- helpers ----------
__device__ __forceinline__ int dot4i8(uint32_t a, uint32_t b, int c) {
#if defined(__has_builtin)
#if __has_builtin(__builtin_amdgcn_sdot4)
  return __builtin_amdgcn_sdot4((int)a, (int)b, c, false);
#else
  int s = c;
  s += (int)(int8_t)(a)       * (int)(int8_t)(b);
  s += (int)(int8_t)(a >> 8)  * (int)(int8_t)(b >> 8);
  s += (int)(int8_t)(a >> 16) * (int)(int8_t)(b >> 16);
  s += (int)(int8_t)(a >> 24) * (int)(int8_t)(b >> 24);
  return s;
#endif
#else
  int s = c;
  s += (int)(int8_t)(a)       * (int)(int8_t)(b);
  s += (int)(int8_t)(a >> 8)  * (int)(int8_t)(b >> 8);
  s += (int)(int8_t)(a >> 16) * (int)(int8_t)(b >> 16);
  s += (int)(int8_t)(a >> 24) * (int)(int8_t)(b >> 24);
  return s;
#endif
}

__device__ __forceinline__ float sigmoidf_fast(float x) {
  return 1.0f / (1.0f + __expf(-x));
}
__device__ __forceinline__ float tanhf_fast(float x) {
  float e = __expf(2.0f * x);
  return 1.0f - 2.0f / (e + 1.0f);
}

// ---------- kernel 1: W -> f16, transposed to [768 n][256 k] ----------
__global__ void conv_w_kernel(const float* __restrict__ Wr,
                              const float* __restrict__ Wz,
                              const float* __restrict__ Wh,
                              half_t* __restrict__ Wt) {
  int n = blockIdx.x;          // 0..767
  int k = threadIdx.x;         // 0..255
  const float* W = (n < 256) ? Wr : ((n < 512) ? Wz : Wh);
  int j = n & 255;
  Wt[(size_t)n * DIM + k] = (half_t)W[(size_t)k * DIM + j];
}

// ---------- kernel 2: a = sigmoid(x@k1 - x@k2) per row ----------
__global__ __launch_bounds__(256) void attn_a_kernel(const float* __restrict__ inp,
                                                     const float* __restrict__ k1,
                                                     const float* __restrict__ k2,
                                                     float* __restrict__ a_arr) {
  int row  = blockIdx.x * 4 + (threadIdx.x >> 6);
  int lane = threadIdx.x & 63;
  const float4* x4 = (const float4*)(inp + (size_t)row * DIM);
  float4 xv  = x4[lane];
  float4 k1v = ((const float4*)k1)[lane];
  float4 k2v = ((const float4*)k2)[lane];
  float e1 = xv.x * k1v.x + xv.y * k1v.y + xv.z * k1v.z + xv.w * k1v.w;
  float e2 = xv.x * k2v.x + xv.y * k2v.y + xv.z * k2v.z + xv.w * k2v.w;
#pragma unroll
  for (int off = 32; off >= 1; off >>= 1) {
    e1 += __shfl_xor(e1, off);
    e2 += __shfl_xor(e2, off);
  }
  if (lane == 0) a_arr[row] = 1.0f / (1.0f + __expf(e2 - e1));
}

// ---------- kernel 2b: per-(gate,col) |U| max -> scale = max/127 ----------
__global__ __launch_bounds__(256) void uscale_kernel(const float* __restrict__ Ur,
                                                     const float* __restrict__ Uz,
                                                     const float* __restrict__ Uh,
                                                     float* __restrict__ su) {
  const int g = blockIdx.x;    // 0..2
  const int j = threadIdx.x;   // 0..255
  const float* U = (g == 0) ? Ur : ((g == 1) ? Uz : Uh);
  float m = 0.0f;
  for (int k = 0; k < DIM; ++k) m = fmaxf(m, fabsf(U[(size_t)k * DIM + j]));
  su[g * DIM + j] = fmaxf(m, 1e-30f) * (1.0f / 127.0f);
}

// ---------- kernel 2c: pack U -> i8 quads, layout Ui8[g][quad=k/4][j] ----------
__global__ __launch_bounds__(256) void upack_kernel(const float* __restrict__ Ur,
                                                    const float* __restrict__ Uz,
                                                    const float* __restrict__ Uh,
                                                    const float* __restrict__ su,
                                                    uint32_t* __restrict__ Ui8) {
  const int g = blockIdx.x;    // 0..2
  const int j = threadIdx.x;   // 0..255
  const float* U = (g == 0) ? Ur : ((g == 1) ? Uz : Uh);
  const float r = 1.0f / su[g * DIM + j];   // = 127/max
  for (int q = 0; q < 64; ++q) {
    uint32_t w = 0;
#pragma unroll
    for (int t = 0; t < 4; ++t) {
      float v = U[(size_t)(q * 4 + t) * DIM + j] * r;
      int mi = __float2int_rn(v);
      mi = mi < -127 ? -127 : (mi > 127 ? 127 : mi);
      w |= ((uint32_t)(mi & 0xFF)) << (8 * t);
    }
    Ui8[((size_t)g * 64 + q) * DIM + j] = w;
  }
}

// ---------- kernel 3: P = X @ [Wr|Wz|Wh]  (MFMA f16, f32 acc, store f16) ----------
__global__ __launch_bounds__(256) void gemm_p_kernel(const float* __restrict__ X,
                                                     const half_t* __restrict__ Wt,
                                                     half_t* __restrict__ P) {
  __shared__ __align__(16) half_t As[128][32];
  __shared__ __align__(16) half_t Bs[128][32];
  const int tid  = threadIdx.x;
  const int bm   = blockIdx.x * 128;
  const int bn   = blockIdx.y * 128;
  const int lane = tid & 63;
  const int wave = tid >> 6;
  const int wm   = (wave >> 1) * 64;
  const int wn   = (wave & 1) * 64;
  const int quad = lane >> 4;
  const int l15  = lane & 15;
  const int r0   = tid >> 2;
  const int kc   = (tid & 3) * 8;

  floatx4 acc[4][4] = {};

  for (int k0 = 0; k0 < DIM; k0 += 32) {
#pragma unroll
    for (int hh = 0; hh < 2; ++hh) {
      int r = r0 + hh * 64;
      const float* asrc = X + (size_t)(bm + r) * DIM + k0 + kc;
      float4 f0 = *(const float4*)(asrc);
      float4 f1 = *(const float4*)(asrc + 4);
      half8_t av;
      av[0] = (half_t)f0.x; av[1] = (half_t)f0.y; av[2] = (half_t)f0.z; av[3] = (half_t)f0.w;
      av[4] = (half_t)f1.x; av[5] = (half_t)f1.y; av[6] = (half_t)f1.z; av[7] = (half_t)f1.w;
      *(half8_t*)(&As[r][kc]) = av;
      *(half8_t*)(&Bs[r][kc]) = *(const half8_t*)(Wt + (size_t)(bn + r) * DIM + k0 + kc);
    }
    __syncthreads();
    half8_t af[4], bf[4];
#pragma unroll
    for (int mi = 0; mi < 4; ++mi)
      af[mi] = *(const half8_t*)(&As[wm + mi * 16 + l15][quad * 8]);
#pragma unroll
    for (int ni = 0; ni < 4; ++ni)
      bf[ni] = *(const half8_t*)(&Bs[wn + ni * 16 + l15][quad * 8]);
#pragma unroll
    for (int mi = 0; mi < 4; ++mi)
#pragma unroll
      for (int ni = 0; ni < 4; ++ni)
        acc[mi][ni] = __builtin_amdgcn_mfma_f32_16x16x32_f16(af[mi], bf[ni], acc[mi][ni], 0, 0, 0);
    __syncthreads();
  }
#pragma unroll
  for (int mi = 0; mi < 4; ++mi)
#pragma unroll
    for (int ni = 0; ni < 4; ++ni) {
      int col = bn + wn + ni * 16 + l15;
#pragma unroll
      for (int rr = 0; rr < 4; ++rr) {
        int row = bm + wm + mi * 16 + quad * 4 + rr;
        P[(size_t)row * 768 + col] = (half_t)acc[mi][ni][rr];
      }
    }
}

// ---------- kernel 4: recurrence, 256 threads, FULL K per thread ----------
// Round-3: same structural experiment as round 2 (U register-residency at
// 1-wave/SIMD occupancy), DE-RISKED: the raw s_barrier + inline-asm
// lgkmcnt-only wait is replaced with plain __syncthreads(). Round 2's
// container failure could not be attributed (infra vs asm-barrier hang);
// everything else here is memory-safe by inspection and matches the round-2
// layout. The vmcnt(0) drain at the barrier costs ~+30us on recur
// (round-1 measurement) — acceptable until residency is confirmed.
//  * 256 threads (4 waves), thread j owns column j for the whole recurrence.
//    __launch_bounds__(256,1) -> up to 512 regs/thread; U = 192 u32 + ~60
//    working set fits arch VGPRs with headroom.
//  * In-loop empty-asm pin each iteration: the allocator may not sink/remat
//    the U loads into the step loop (round-0/1 hidden per-step cost,
//    VGPR_Count=88 was the tell).
//  * Full-K per thread deletes the pair-combine shuffles; one barrier/step
//    with double-buffered mtb.
__global__ __launch_bounds__(256, 1) void recur_kernel(
    const half_t* __restrict__ P,     // [32768, 768] f16 (xWr | xWz | xWh)
    const float* __restrict__ a_arr,  // [32768]
    const int* __restrict__ cidx,     // [32768]
    const uint32_t* __restrict__ Ui8, // [3][64][256] packed i8 quads
    const float* __restrict__ su,     // [3][256] scales (max/127)
    const float* __restrict__ br, const float* __restrict__ bz, const float* __restrict__ bh,
    float* __restrict__ out) {        // [32768, 256] f32
  const int j = threadIdx.x;          // 0..255 (column)

  __shared__ __align__(16) half_t   hist[SEQ_L][128];  // 128 KB (cols 128..255)
  __shared__ __align__(16) uint32_t mtb[2][64];        // 512 B, double-buffered mt (i8)

  // ---- register-resident U: 48 u32x4 = 192 u32 of packed i8 quads ----
  u32x4 ur8[16], uz8[16], uh8[16];
#pragma unroll
  for (int c8 = 0; c8 < 16; ++c8) {
#pragma unroll
    for (int t = 0; t < 4; ++t) {
      const int quad = c8 * 4 + t;
      ur8[c8][t] = Ui8[((size_t)0 * 64 + quad) * DIM + j];
      uz8[c8][t] = Ui8[((size_t)1 * 64 + quad) * DIM + j];
      uh8[c8][t] = Ui8[((size_t)2 * 64 + quad) * DIM + j];
    }
  }

  const float scr = su[0 * DIM + j] * (1.0f / 127.0f);
  const float scz = su[1 * DIM + j] * (1.0f / 127.0f);
  const float sch = su[2 * DIM + j] * (1.0f / 127.0f);
  const float brj = br[j], bzj = bz[j], bhj = bh[j];

  // step 0 has mt == 0 (h0 = 0, c0 = 0)
  if (j < 64) mtb[0][j] = 0u;

  float mtj = 0.0f;                   // current step's mt[j] (f32, exact)
  const int base = blockIdx.x * SEQ_L;

  // ---- prefetch state for step 0 ----
  const half_t* prow0 = P + (size_t)base * 768;
  float pr_c = (float)prow0[j];
  float pz_c = (float)prow0[DIM + j];
  float ph_c = (float)prow0[2 * DIM + j];
  float a_n = a_arr[base + 1];
  int   c_n = cidx[base + 1];

  __syncthreads();   // publishes mtb[0]

  for (int i = 0; i < SEQ_L; ++i) {
    // ---- pin U into arch VGPRs EVERY iteration: remat/sink is now illegal ----
#pragma unroll
    for (int g8 = 0; g8 < 2; ++g8) {
      asm volatile("" : "+v"(ur8[g8*8+0]), "+v"(ur8[g8*8+1]), "+v"(ur8[g8*8+2]), "+v"(ur8[g8*8+3]),
                         "+v"(ur8[g8*8+4]), "+v"(ur8[g8*8+5]), "+v"(ur8[g8*8+6]), "+v"(ur8[g8*8+7]));
      asm volatile("" : "+v"(uz8[g8*8+0]), "+v"(uz8[g8*8+1]), "+v"(uz8[g8*8+2]), "+v"(uz8[g8*8+3]),
                         "+v"(uz8[g8*8+4]), "+v"(uz8[g8*8+5]), "+v"(uz8[g8*8+6]), "+v"(uz8[g8*8+7]));
      asm volatile("" : "+v"(uh8[g8*8+0]), "+v"(uh8[g8*8+1]), "+v"(uh8[g8*8+2]), "+v"(uh8[g8*8+3]),
                         "+v"(uh8[g8*8+4]), "+v"(uh8[g8*8+5]), "+v"(uh8[g8*8+6]), "+v"(uh8[g8*8+7]));
    }

    // ---- coref prefetch for next step's mt: overlaps the dot phase ----
    const int  cp    = c_n - 1;          // <= i (valid coref constraint)
    const bool use_h = (cp == i);        // block-uniform
    float corefv = 0.0f;
    if (j >= 128) {                      // waves 2..3, wave-uniform
      if (c_n > 0 && !use_h) corefv = (float)hist[cp][j - 128];
    }

    // ---- next-step global prefetch; consumed a full step later ----
    const int ip1 = (i + 1 < SEQ_L) ? (i + 1) : i;
    const half_t* prow = P + (size_t)(base + ip1) * 768;
    float pr_x = (float)prow[j];
    float pz_x = (float)prow[DIM + j];
    float ph_x = (float)prow[2 * DIM + j];
    const int ip2 = (i + 2 < SEQ_L) ? (i + 2) : (SEQ_L - 1);
    const float a_x = a_arr[base + ip2];
    const int   c_x = cidx[base + ip2];

    // ---- i8 dots over the FULL 256-element K (64 quads) ----
    int ar = 0, az = 0, ah = 0;
    const u32x4* mq = (const u32x4*)(&mtb[i & 1][0]);
#pragma unroll
    for (int c8 = 0; c8 < 16; ++c8) {
      u32x4 m4 = mq[c8];                 // ds_read_b128, same-addr broadcast
      ar = dot4i8(m4.x, ur8[c8][0], ar);
      az = dot4i8(m4.x, uz8[c8][0], az);
      ah = dot4i8(m4.x, uh8[c8][0], ah);
      ar = dot4i8(m4.y, ur8[c8][1], ar);
      az = dot4i8(m4.y, uz8[c8][1], az);
      ah = dot4i8(m4.y, uh8[c8][1], ah);
      ar = dot4i8(m4.z, ur8[c8][2], ar);
      az = dot4i8(m4.z, uz8[c8][2], az);
      ah = dot4i8(m4.z, uh8[c8][2], ah);
      ar = dot4i8(m4.w, ur8[c8][3], ar);
      az = dot4i8(m4.w, uz8[c8][3], az);
      ah = dot4i8(m4.w, uh8[c8][3], ah);
    }

    const float fr = (float)ar * scr;
    const float fz = (float)az * scz;
    const float fh = (float)ah * sch;
    const float rg = sigmoidf_fast(pr_c + brj + fr);
    const float zg = sigmoidf_fast(pz_c + bzj + fz);
    const float hb = tanhf_fast(ph_c + bhj + rg * fh);
    const float h  = (1.0f - zg) * mtj + zg * hb;

    // ---- writes ----
    out[(size_t)(base + i) * DIM + j] = h;
    if (j >= 128) hist[i][j - 128] = (half_t)h;

    // ---- next step's mt (f32 exact for the recurrent path) ----
    float mtn;
    if (j < 128) {
      mtn = a_n * h;
    } else {
      const float coref = (c_n > 0) ? (use_h ? h : corefv) : 0.0f;
      mtn = (1.0f - a_n) * coref;
    }
    mtj = mtn;

    // ---- quantize + pack 4 columns' bytes -> one u32 (|mt| <= 1) ----
    int mi = __float2int_rn(mtn * 127.0f);
    mi = mi < -127 ? -127 : (mi > 127 ? 127 : mi);
    unsigned v0 = (unsigned)mi & 0xFFu;
    unsigned o1 = (unsigned)__shfl_xor((int)v0, 1) & 0xFFu;   // byte of col j^1
    unsigned pp = (j & 1) ? (o1 | (v0 << 8)) : (v0 | (o1 << 8));
    unsigned o2 = (unsigned)__shfl_xor((int)pp, 2);           // halfword of pair j^2
    unsigned qd = (j & 2) ? ((o2 & 0xFFFFu) | (pp << 16))
                          : ((pp & 0xFFFFu) | (o2 << 16));
    if ((j & 3) == 0) mtb[(i + 1) & 1][j >> 2] = qd;

    // rotate prefetch registers
    pr_c = pr_x; pz_c = pz_x; ph_c = ph_x;
    a_n = a_x;   c_n = c_x;

    // barrier: publishes mtb[(i+1)&1] + hist[i]; also separates step-i reads
    // of mtb[i&1] from step-(i+1) writes into that same buffer.
    __syncthreads();
  }
}

// ---------- launcher ----------
extern "C" void kernel_launch(void* const* d_in, const int* in_sizes, int n_in,
                              void* d_out, int out_size, void* d_ws, size_t ws_size,
                              hipStream_t stream) {
  const float* inp = (const float*)d_in[0];
  const int*   ci  = (const int*)d_in[1];
  const float* Wr  = (const float*)d_in[2];
  const float* br  = (const float*)d_in[3];
  const float* Ur  = (const float*)d_in[4];
  const float* Wz  = (const float*)d_in[5];
  const float* bz  = (const float*)d_in[6];
  const float* Uz  = (const float*)d_in[7];
  const float* Wh  = (const float*)d_in[8];
  const float* bh  = (const float*)d_in[9];
  const float* Uh  = (const float*)d_in[10];
  const float* k1  = (const float*)d_in[11];
  const float* k2  = (const float*)d_in[12];
  float* out = (float*)d_out;

  char* ws = (char*)d_ws;
  // ws carve: Wt f16 [768*256] | P f16 [32768*768] | a f32 [32768]
  //           | su f32 [3*256] | Ui8 u32 [3*64*256]
  half_t*   Wt    = (half_t*)ws;                               // 393216 B
  half_t*   P     = (half_t*)(ws + 393216);                    // 50331648 B
  float*    a_arr = (float*)(ws + 393216 + 50331648);          // 131072 B
  float*    su    = (float*)(ws + 50855936);                   // 3072 B
  uint32_t* Ui8   = (uint32_t*)(ws + 50859008);                // 196608 B

  conv_w_kernel<<<dim3(768), dim3(256), 0, stream>>>(Wr, Wz, Wh, Wt);
  attn_a_kernel<<<dim3(NTOT / 4), dim3(256), 0, stream>>>(inp, k1, k2, a_arr);
  uscale_kernel<<<dim3(3), dim3(256), 0, stream>>>(Ur, Uz, Uh, su);
  upack_kernel<<<dim3(3), dim3(256), 0, stream>>>(Ur, Uz, Uh, su, Ui8);
  gemm_p_kernel<<<dim3(NTOT / 128, 6), dim3(256), 0, stream>>>(inp, Wt, P);
  recur_kernel<<<dim3(NBATCH), dim3(256), 0, stream>>>(P, a_arr, ci, Ui8, su,
                                                       br, bz, bh, out);
}